// Round 4
// baseline (249.285 us; speedup 1.0000x reference)
//
#include <hip/hip_runtime.h>
#include <stdint.h>

typedef __attribute__((ext_vector_type(8))) short s16x8;
typedef __attribute__((ext_vector_type(4))) float f32x4;

#define DIM 1024
#define NQ 4096
#define NDOC 8192
#define NKT 16          // K-tiles of 64

__device__ __forceinline__ unsigned f2bf(float f) {
    unsigned int u = __builtin_bit_cast(unsigned int, f);
    u += 0x7FFFu + ((u >> 16) & 1u);   // RNE
    return u >> 16;
}
__device__ __forceinline__ float bf2f(unsigned int s) {
    unsigned int u = (s & 0xFFFFu) << 16;
    return __builtin_bit_cast(float, u);
}
template<int N> __device__ __forceinline__ void wait_vm() {
    if constexpr (N == 4)      asm volatile("s_waitcnt vmcnt(4)" ::: "memory");
    else                       asm volatile("s_waitcnt vmcnt(0)" ::: "memory");
}

// ---------------- kernel 1: L2-normalize rows -> bf16 (one wave per row) ----------------
__global__ __launch_bounds__(256) void normalize_kernel(
    const float* __restrict__ q, const float* __restrict__ pos,
    const float* __restrict__ neg, unsigned short* __restrict__ qn,
    unsigned short* __restrict__ dn, float* __restrict__ rowsum) {
    int row = blockIdx.x * 4 + (threadIdx.x >> 6);
    int lane = threadIdx.x & 63;
    const float* src;
    unsigned short* dst;
    if (row < 4096) {
        src = q + (size_t)row * DIM; dst = qn + (size_t)row * DIM;
        if (lane == 0) rowsum[row] = 0.f;
    } else if (row < 8192) {
        src = pos + (size_t)(row - 4096) * DIM; dst = dn + (size_t)(row - 4096) * DIM;
    } else {
        src = neg + (size_t)(row - 8192) * DIM; dst = dn + (size_t)(row - 4096) * DIM;
    }
    float4 v[4];
    float ss = 0.f;
#pragma unroll
    for (int it = 0; it < 4; ++it) {
        v[it] = reinterpret_cast<const float4*>(src)[it * 64 + lane];
        ss += v[it].x * v[it].x + v[it].y * v[it].y + v[it].z * v[it].z + v[it].w * v[it].w;
    }
#pragma unroll
    for (int off = 32; off > 0; off >>= 1) ss += __shfl_xor(ss, off, 64);
    float inv = rsqrtf(ss);
#pragma unroll
    for (int it = 0; it < 4; ++it) {
        uint2 o;
        o.x = f2bf(v[it].x * inv) | (f2bf(v[it].y * inv) << 16);
        o.y = f2bf(v[it].z * inv) | (f2bf(v[it].w * inv) << 16);
        reinterpret_cast<uint2*>(dst)[it * 64 + lane] = o;
    }
}

// ---------------- kernel 2: 256x256 GEMM, BK=64, m201-style 4-phase schedule ------------
// LDS: 2 buffers x 64 KB. Buffer (elems): A [ksl 0..7][row 0..255][8] at +0,
// B same at +16384. Frag: elem = ks*4096 + lk*2048 + row*8 (+mtile*128).
// Stage: thread tid, round r -> chunk c = r*512+tid: ksl=c>>8, row=c&255,
// dest elem = c*8 (linear, gload_lds-compatible); source pre-permuted.
#define GLOAD_LDS(g, l) __builtin_amdgcn_global_load_lds( \
    (const __attribute__((address_space(1))) void*)(g),   \
    (__attribute__((address_space(3))) void*)(l), 16, 0, 0)

#define STAGE2(nbe, kt, r) {                                          \
    const unsigned short* sA_ = aSrc + (kt) * 64 + (r) * 16;          \
    const unsigned short* sB_ = bSrc + (kt) * 64 + (r) * 16;         \
    unsigned short* dA_ = lds + (nbe) + (r) * 4096 + tid * 8;         \
    unsigned short* dB_ = lds + (nbe) + 16384 + (r) * 4096 + tid * 8; \
    GLOAD_LDS(sA_, dA_);                                              \
    GLOAD_LDS(sB_, dB_);                                              \
  }

// One phase: (k-step KS, m-half H). DOB: reload B frags (KS changed).
// {reads ; stage 2 loads ; barrier ; [compiler lgkm] ; prio1 ; 16 MFMA ; prio0}
#define PHASE(KS, H, DOB, DOSTAGE, R) {                                        \
    if (DOB) {                                                                 \
        _Pragma("unroll") for (int n = 0; n < 4; ++n)                          \
            bF[n] = *reinterpret_cast<const s16x8*>(                           \
                lds + bBaseE + bufe + (KS) * 4096 + n * 128);                  \
    }                                                                          \
    s16x8 aF[4];                                                               \
    _Pragma("unroll") for (int m = 0; m < 4; ++m)                              \
        aF[m] = *reinterpret_cast<const s16x8*>(                               \
            lds + aBaseE + bufe + (KS) * 4096 + ((H) * 4 + m) * 128);          \
    if (DOSTAGE) STAGE2(nbe, t + 1, R);                                        \
    __builtin_amdgcn_s_barrier();                                              \
    __builtin_amdgcn_s_setprio(1);                                             \
    _Pragma("unroll") for (int m = 0; m < 4; ++m)                              \
        _Pragma("unroll") for (int n = 0; n < 4; ++n)                          \
            acc[(H) * 4 + m][n] = __builtin_amdgcn_mfma_f32_16x16x32_bf16(     \
                aF[m], bF[n], acc[(H) * 4 + m][n], 0, 0, 0);                   \
    __builtin_amdgcn_s_setprio(0);                                             \
  }

__global__ __launch_bounds__(512, 2) void gemm_lse_kernel(
    const unsigned short* __restrict__ qn, const unsigned short* __restrict__ dn,
    float* __restrict__ rowsum) {
    extern __shared__ unsigned short lds[];   // 131072 bytes = 65536 elems
    const int tid = threadIdx.x;
    const int lane = tid & 63;
    const int wid = tid >> 6;
    const int wr = wid >> 2;        // 0..1  (128-row half)
    const int wc = wid & 3;         // 0..3  (64-col slice)
    const int lr = lane & 15;
    const int lk = lane >> 4;

    // XCD-aware blocked swizzle: each XCD owns an 8x8 region of the 16x32 grid
    int bid = blockIdx.x;
    int xcd = bid & 7, local = bid >> 3;
    int brow = (xcd >> 2) * 8 + (local >> 3);   // 0..15
    int bcol = (xcd & 3) * 8 + (local & 7);     // 0..31

    const unsigned short* aSrc = qn + (size_t)(brow * 256 + (tid & 255)) * DIM + (tid >> 8) * 8;
    const unsigned short* bSrc = dn + (size_t)(bcol * 256 + (tid & 255)) * DIM + (tid >> 8) * 8;

    const int aBaseE = lk * 2048 + (wr * 128 + lr) * 8;
    const int bBaseE = 16384 + lk * 2048 + (wc * 64 + lr) * 8;

    f32x4 acc[8][4] = {};

    // prologue: stage tile 0 into buffer 0 (queue: A0,B0,A1,B1,A2,B2,A3,B3)
#pragma unroll
    for (int r = 0; r < 4; ++r) STAGE2(0, 0, r);
    wait_vm<4>();                 // A/B k-slices 0..3 (H0) landed
    __builtin_amdgcn_s_barrier();

    for (int t = 0; t < NKT; ++t) {
        const int bufe = (t & 1) * 32768;
        const int nbe  = bufe ^ 32768;
        const bool st  = (t < NKT - 1);
        s16x8 bF[4];
        PHASE(0, 0, true,  st, 0)
        __builtin_amdgcn_s_barrier();
        PHASE(0, 1, false, st, 1)
        if (st) wait_vm<4>(); else wait_vm<0>();   // H1(t) landed
        __builtin_amdgcn_s_barrier();
        PHASE(1, 0, true,  st, 2)
        __builtin_amdgcn_s_barrier();
        PHASE(1, 1, false, st, 3)
        if (st) wait_vm<4>(); else wait_vm<0>();   // H0(t+1) landed
        __builtin_amdgcn_s_barrier();
    }

    // epilogue: rowsum[row] += sum_cols exp(20*s - 20)
    // C/D: col = wc*64 + n*16 + lr, row = brow*256 + wr*128 + m*16 + lk*4 + j
#pragma unroll
    for (int m = 0; m < 8; ++m) {
#pragma unroll
        for (int j = 0; j < 4; ++j) {
            float r = 0.f;
#pragma unroll
            for (int n = 0; n < 4; ++n) {
                float s = 20.f * acc[m][n][j] - 20.f;
                r += __expf(s);
            }
#pragma unroll
            for (int off = 1; off < 16; off <<= 1) r += __shfl_xor(r, off, 64);
            if (lr == 0) {
                int row = brow * 256 + wr * 128 + m * 16 + lk * 4 + j;
                atomicAdd(&rowsum[row], r);
            }
        }
    }
}

// ---------------- kernel 3: per-row diag + lse (one wave per row) ----------------
__global__ __launch_bounds__(256) void loss_kernel(
    const unsigned short* __restrict__ qn, const unsigned short* __restrict__ dn,
    const float* __restrict__ rowsum, float* __restrict__ rowloss) {
    int row = blockIdx.x * 4 + (threadIdx.x >> 6);
    int lane = threadIdx.x & 63;
    const uint4* a4 = reinterpret_cast<const uint4*>(qn + (size_t)row * DIM);
    const uint4* b4 = reinterpret_cast<const uint4*>(dn + (size_t)row * DIM);
    float s = 0.f;
#pragma unroll
    for (int it = 0; it < 2; ++it) {
        uint4 ua = a4[it * 64 + lane], ub = b4[it * 64 + lane];
        s += bf2f(ua.x) * bf2f(ub.x) + bf2f(ua.x >> 16) * bf2f(ub.x >> 16);
        s += bf2f(ua.y) * bf2f(ub.y) + bf2f(ua.y >> 16) * bf2f(ub.y >> 16);
        s += bf2f(ua.z) * bf2f(ub.z) + bf2f(ua.z >> 16) * bf2f(ub.z >> 16);
        s += bf2f(ua.w) * bf2f(ub.w) + bf2f(ua.w >> 16) * bf2f(ub.w >> 16);
    }
#pragma unroll
    for (int off = 32; off > 0; off >>= 1) s += __shfl_xor(s, off, 64);
    if (lane == 0)
        rowloss[row] = (20.f + __logf(rowsum[row])) - 20.f * s;
}

// ---------------- kernel 4: mean over 4096 row losses ----------------
__global__ __launch_bounds__(1024) void reduce_kernel(
    const float* __restrict__ rowloss, float* __restrict__ out) {
    int t = threadIdx.x;
    float s = 0.f;
#pragma unroll
    for (int i = 0; i < 4; ++i) s += rowloss[t + i * 1024];
#pragma unroll
    for (int off = 32; off > 0; off >>= 1) s += __shfl_xor(s, off, 64);
    __shared__ float wsum[16];
    if ((t & 63) == 0) wsum[t >> 6] = s;
    __syncthreads();
    if (t == 0) {
        float tot = 0.f;
#pragma unroll
        for (int i = 0; i < 16; ++i) tot += wsum[i];
        out[0] = tot * (1.f / 4096.f);
    }
}

extern "C" void kernel_launch(void* const* d_in, const int* in_sizes, int n_in,
                              void* d_out, int out_size, void* d_ws, size_t ws_size,
                              hipStream_t stream) {
    const float* q   = (const float*)d_in[0];
    const float* pos = (const float*)d_in[1];
    const float* neg = (const float*)d_in[2];
    float* out = (float*)d_out;
    char* ws = (char*)d_ws;
    unsigned short* qn = (unsigned short*)ws;                                 // 8 MB
    unsigned short* dn = (unsigned short*)(ws + (size_t)8 * 1024 * 1024);     // 16 MB
    float* rowsum  = (float*)(ws + (size_t)24 * 1024 * 1024);                 // 16 KB
    float* rowloss = (float*)(ws + (size_t)24 * 1024 * 1024 + 16384);         // 16 KB

    static bool attr_set = false;
    if (!attr_set) {
        (void)hipFuncSetAttribute((const void*)gemm_lse_kernel,
                                  hipFuncAttributeMaxDynamicSharedMemorySize, 131072);
        attr_set = true;
    }

    normalize_kernel<<<3072, 256, 0, stream>>>(q, pos, neg, qn, dn, rowsum);
    gemm_lse_kernel<<<512, 512, 131072, stream>>>(qn, dn, rowsum);
    loss_kernel<<<1024, 256, 0, stream>>>(qn, dn, rowsum, rowloss);
    reduce_kernel<<<1, 1024, 0, stream>>>(rowloss, out);
}

// Round 5
// 171.335 us; speedup vs baseline: 1.4550x; 1.4550x over previous
//
#include <hip/hip_runtime.h>
#include <stdint.h>

typedef __attribute__((ext_vector_type(8))) short s16x8;
typedef __attribute__((ext_vector_type(4))) float f32x4;

#define DIM 1024
#define NQ 4096
#define NDOC 8192
#define NKT 16          // K-tiles of 64

__device__ __forceinline__ unsigned f2bf(float f) {
    unsigned int u = __builtin_bit_cast(unsigned int, f);
    u += 0x7FFFu + ((u >> 16) & 1u);   // RNE
    return u >> 16;
}
__device__ __forceinline__ float bf2f(unsigned int s) {
    unsigned int u = (s & 0xFFFFu) << 16;
    return __builtin_bit_cast(float, u);
}

// ---------------- kernel 1: L2-normalize rows -> bf16 (one wave per row) ----------------
__global__ __launch_bounds__(256) void normalize_kernel(
    const float* __restrict__ q, const float* __restrict__ pos,
    const float* __restrict__ neg, unsigned short* __restrict__ qn,
    unsigned short* __restrict__ dn, float* __restrict__ rowsum) {
    int row = blockIdx.x * 4 + (threadIdx.x >> 6);
    int lane = threadIdx.x & 63;
    const float* src;
    unsigned short* dst;
    if (row < 4096) {
        src = q + (size_t)row * DIM; dst = qn + (size_t)row * DIM;
        if (lane == 0) rowsum[row] = 0.f;
    } else if (row < 8192) {
        src = pos + (size_t)(row - 4096) * DIM; dst = dn + (size_t)(row - 4096) * DIM;
    } else {
        src = neg + (size_t)(row - 8192) * DIM; dst = dn + (size_t)(row - 4096) * DIM;
    }
    float4 v[4];
    float ss = 0.f;
#pragma unroll
    for (int it = 0; it < 4; ++it) {
        v[it] = reinterpret_cast<const float4*>(src)[it * 64 + lane];
        ss += v[it].x * v[it].x + v[it].y * v[it].y + v[it].z * v[it].z + v[it].w * v[it].w;
    }
#pragma unroll
    for (int off = 32; off > 0; off >>= 1) ss += __shfl_xor(ss, off, 64);
    float inv = rsqrtf(ss);
#pragma unroll
    for (int it = 0; it < 4; ++it) {
        uint2 o;
        o.x = f2bf(v[it].x * inv) | (f2bf(v[it].y * inv) << 16);
        o.y = f2bf(v[it].z * inv) | (f2bf(v[it].w * inv) << 16);
        reinterpret_cast<uint2*>(dst)[it * 64 + lane] = o;
    }
}

// ---------------- kernel 2: 256x256 GEMM, BK=64, coalesced swizzled staging -------------
// LDS: 2 buffers x 64 KB. Buffer: A rows [256][64 bf16] at +0 (row stride 128 B),
// B same at +32768. Swizzle: LDS[row][slot] = G[row][slot ^ (row&7)] (slot = 16B unit).
// Staging: chunk c = r*512+tid -> row=c>>3, slot=c&7; dest byte = c*16 (linear, wave =
// 8 rows x 128 B contiguous global per row -> full-line coalescing).
// Frag read: row = <tile row> + lr, slot = (KS*4+lk) ^ (lr&7) -> 2-way bank alias (free).
#define GLOAD_LDS(g, l) __builtin_amdgcn_global_load_lds( \
    (const __attribute__((address_space(1))) void*)(g),   \
    (__attribute__((address_space(3))) void*)(l), 16, 0, 0)

#define STG(kt, r, bufByte) {                                                     \
    GLOAD_LDS(aG + (r) * 65536 + (kt) * 64, ldsc + (bufByte) + ((r) * 512 + tid) * 16); \
    GLOAD_LDS(bG + (r) * 65536 + (kt) * 64, ldsc + (bufByte) + 32768 + ((r) * 512 + tid) * 16); \
  }

// phase: {frag reads ; optional 2 staged loads ; barrier ; prio1 ; 16 MFMA ; prio0}
#define PHASE(CUR, KS, H, DOB, DOSTG, KT1, R) {                                   \
    if (DOB) {                                                                    \
        _Pragma("unroll") for (int n = 0; n < 4; ++n)                             \
            bF[n] = *(const s16x8*)(ldsc + (CUR) + (bB0 ^ ((KS) * 64)) + n * 2048); \
    }                                                                             \
    s16x8 aF[4];                                                                  \
    _Pragma("unroll") for (int m = 0; m < 4; ++m)                                 \
        aF[m] = *(const s16x8*)(ldsc + (CUR) + (aB0 ^ ((KS) * 64)) + ((H) * 64 + m * 16) * 128); \
    if (DOSTG) STG(KT1, R, (CUR) ^ 65536);                                        \
    __builtin_amdgcn_s_barrier();                                                 \
    __builtin_amdgcn_s_setprio(1);                                                \
    _Pragma("unroll") for (int m = 0; m < 4; ++m)                                 \
        _Pragma("unroll") for (int n = 0; n < 4; ++n)                             \
            acc[(H) * 4 + m][n] = __builtin_amdgcn_mfma_f32_16x16x32_bf16(        \
                aF[m], bF[n], acc[(H) * 4 + m][n], 0, 0, 0);                      \
    __builtin_amdgcn_s_setprio(0);                                                \
  }

__global__ __launch_bounds__(512, 2) void gemm_lse_kernel(
    const unsigned short* __restrict__ qn, const unsigned short* __restrict__ dn,
    float* __restrict__ rowsum) {
    extern __shared__ char ldsc[];   // 131072 bytes
    const int tid = threadIdx.x;
    const int lane = tid & 63;
    const int wid = tid >> 6;
    const int wr = wid >> 2;        // 0..1  (128-row half)
    const int wc = wid & 3;         // 0..3  (64-col slice)
    const int lr = lane & 15;
    const int lk = lane >> 4;

    // XCD-aware blocked swizzle: each XCD owns an 8x8 region of the 16x32 grid
    int bid = blockIdx.x;
    int xcd = bid & 7, local = bid >> 3;
    int brow = (xcd >> 2) * 8 + (local >> 3);   // 0..15
    int bcol = (xcd & 3) * 8 + (local & 7);     // 0..31

    // staging source (pre-swizzled slot within the same 128 B line)
    const int srow = tid >> 3;                       // 0..63 (+ r*64)
    const int sslot = (tid & 7) ^ (srow & 7);        // inverse-permuted 16B unit
    const unsigned short* aG = qn + (size_t)(brow * 256 + srow) * DIM + sslot * 8;
    const unsigned short* bG = dn + (size_t)(bcol * 256 + srow) * DIM + sslot * 8;

    // fragment read bases (bytes within buffer); KS toggles bit 6 (slot ^= 4)
    const int s0 = lk ^ (lane & 7);
    const int aB0 = (wr * 128 + lr) * 128 + s0 * 16;
    const int bB0 = 32768 + (wc * 64 + lr) * 128 + s0 * 16;

    f32x4 acc[8][4] = {};

    // prologue: tile 0 fully (rounds 0-3) into buf 0, round 0 of tile 1 into buf 1
#pragma unroll
    for (int r = 0; r < 4; ++r) STG(0, r, 0);
    STG(1, 0, 65536);
    asm volatile("s_waitcnt vmcnt(2)" ::: "memory");   // tile 0 landed; 2 in flight
    __builtin_amdgcn_s_barrier();

    for (int t = 0; t < NKT; ++t) {
        const int cur = (t & 1) ? 65536 : 0;
        const bool st = t < NKT - 1;
        s16x8 bF[4];
        PHASE(cur, 0, 0, true,  st, t + 1, 1)
        PHASE(cur, 0, 1, false, st, t + 1, 2)
        PHASE(cur, 1, 0, true,  st, t + 1, 3)
        PHASE(cur, 1, 1, false, false, 0, 0)
        if (t < NKT - 2) {
            __builtin_amdgcn_s_barrier();      // all waves' reads of cur drained
            STG(t + 2, 0, cur);                // pre-issue round 0 of tile t+2
            asm volatile("s_waitcnt vmcnt(2)" ::: "memory");  // tile t+1 complete
            __builtin_amdgcn_s_barrier();
        } else if (t == NKT - 2) {
            __builtin_amdgcn_s_barrier();
            asm volatile("s_waitcnt vmcnt(0)" ::: "memory");  // last tile complete
            __builtin_amdgcn_s_barrier();
        }
    }

    // epilogue: rowsum[row] += sum_cols exp(20*s - 20)
    // C/D: col = wc*64 + n*16 + lr, row = brow*256 + wr*128 + m*16 + lk*4 + j
#pragma unroll
    for (int m = 0; m < 8; ++m) {
#pragma unroll
        for (int j = 0; j < 4; ++j) {
            float r = 0.f;
#pragma unroll
            for (int n = 0; n < 4; ++n) {
                float s = 20.f * acc[m][n][j] - 20.f;
                r += __expf(s);
            }
#pragma unroll
            for (int off = 1; off < 16; off <<= 1) r += __shfl_xor(r, off, 64);
            if (lr == 0) {
                int row = brow * 256 + wr * 128 + m * 16 + lk * 4 + j;
                atomicAdd(&rowsum[row], r);
            }
        }
    }
}

// ---------------- kernel 3: per-row diag + lse (one wave per row) ----------------
__global__ __launch_bounds__(256) void loss_kernel(
    const unsigned short* __restrict__ qn, const unsigned short* __restrict__ dn,
    const float* __restrict__ rowsum, float* __restrict__ rowloss) {
    int row = blockIdx.x * 4 + (threadIdx.x >> 6);
    int lane = threadIdx.x & 63;
    const uint4* a4 = reinterpret_cast<const uint4*>(qn + (size_t)row * DIM);
    const uint4* b4 = reinterpret_cast<const uint4*>(dn + (size_t)row * DIM);
    float s = 0.f;
#pragma unroll
    for (int it = 0; it < 2; ++it) {
        uint4 ua = a4[it * 64 + lane], ub = b4[it * 64 + lane];
        s += bf2f(ua.x) * bf2f(ub.x) + bf2f(ua.x >> 16) * bf2f(ub.x >> 16);
        s += bf2f(ua.y) * bf2f(ub.y) + bf2f(ua.y >> 16) * bf2f(ub.y >> 16);
        s += bf2f(ua.z) * bf2f(ub.z) + bf2f(ua.z >> 16) * bf2f(ub.z >> 16);
        s += bf2f(ua.w) * bf2f(ub.w) + bf2f(ua.w >> 16) * bf2f(ub.w >> 16);
    }
#pragma unroll
    for (int off = 32; off > 0; off >>= 1) s += __shfl_xor(s, off, 64);
    if (lane == 0)
        rowloss[row] = (20.f + __logf(rowsum[row])) - 20.f * s;
}

// ---------------- kernel 4: mean over 4096 row losses ----------------
__global__ __launch_bounds__(1024) void reduce_kernel(
    const float* __restrict__ rowloss, float* __restrict__ out) {
    int t = threadIdx.x;
    float s = 0.f;
#pragma unroll
    for (int i = 0; i < 4; ++i) s += rowloss[t + i * 1024];
#pragma unroll
    for (int off = 32; off > 0; off >>= 1) s += __shfl_xor(s, off, 64);
    __shared__ float wsum[16];
    if ((t & 63) == 0) wsum[t >> 6] = s;
    __syncthreads();
    if (t == 0) {
        float tot = 0.f;
#pragma unroll
        for (int i = 0; i < 16; ++i) tot += wsum[i];
        out[0] = tot * (1.f / 4096.f);
    }
}

extern "C" void kernel_launch(void* const* d_in, const int* in_sizes, int n_in,
                              void* d_out, int out_size, void* d_ws, size_t ws_size,
                              hipStream_t stream) {
    const float* q   = (const float*)d_in[0];
    const float* pos = (const float*)d_in[1];
    const float* neg = (const float*)d_in[2];
    float* out = (float*)d_out;
    char* ws = (char*)d_ws;
    unsigned short* qn = (unsigned short*)ws;                                 // 8 MB
    unsigned short* dn = (unsigned short*)(ws + (size_t)8 * 1024 * 1024);     // 16 MB
    float* rowsum  = (float*)(ws + (size_t)24 * 1024 * 1024);                 // 16 KB
    float* rowloss = (float*)(ws + (size_t)24 * 1024 * 1024 + 16384);         // 16 KB

    static bool attr_set = false;
    if (!attr_set) {
        (void)hipFuncSetAttribute((const void*)gemm_lse_kernel,
                                  hipFuncAttributeMaxDynamicSharedMemorySize, 131072);
        attr_set = true;
    }

    normalize_kernel<<<3072, 256, 0, stream>>>(q, pos, neg, qn, dn, rowsum);
    gemm_lse_kernel<<<512, 512, 131072, stream>>>(qn, dn, rowsum);
    loss_kernel<<<1024, 256, 0, stream>>>(qn, dn, rowsum, rowloss);
    reduce_kernel<<<1, 1024, 0, stream>>>(rowloss, out);
}